// Round 3
// baseline (16.483 us; speedup 1.0000x reference)
//
#include <hip/hip_runtime.h>

// B=128, G=1024, D=128. Outputs: g_bf (B,D) then g_af (B,D), f32.
constexpr int Bq = 128;
constexpr int Gq = 1024;
constexpr int Dq = 128;
constexpr int NDC = 8;  // d-chunks of 16 floats (64 B) each -> grid 128 x 8

__global__ __launch_bounds__(512, 8) void agg_kernel(
    const float* __restrict__ h,     // (B, G, D)
    const float* __restrict__ adj,   // (B, G, G)
    const int*   __restrict__ phone, // (B,)
    float*       __restrict__ out)   // [g_bf (B,D) | g_af (B,D)]
{
    const int b  = blockIdx.x;   // batch
    const int dc = blockIdx.y;   // d-chunk (16 floats)
    const int t  = threadIdx.x;  // 0..511
    const int p  = phone[b];

    // Stage pre-masked pivot-row weights: row_bf[g] = (g<p)?row:0,
    // row_af[g] = (g>p)?row:0. Coalesced float4 loads by first 256 threads.
    __shared__ float row_bf_s[Gq];
    __shared__ float row_af_s[Gq];
    if (t < 256) {
        const int j = t << 2;
        const float4 r = *reinterpret_cast<const float4*>(
            adj + ((long long)b * Gq + (long long)p) * Gq + j);
        float4 rb, ra;
        rb.x = (j + 0 < p) ? r.x : 0.0f;  ra.x = (j + 0 > p) ? r.x : 0.0f;
        rb.y = (j + 1 < p) ? r.y : 0.0f;  ra.y = (j + 1 > p) ? r.y : 0.0f;
        rb.z = (j + 2 < p) ? r.z : 0.0f;  ra.z = (j + 2 > p) ? r.z : 0.0f;
        rb.w = (j + 3 < p) ? r.w : 0.0f;  ra.w = (j + 3 > p) ? r.w : 0.0f;
        *reinterpret_cast<float4*>(row_bf_s + j) = rb;
        *reinterpret_cast<float4*>(row_af_s + j) = ra;
    }
    __syncthreads();

    // Thread t: d-slot (t&3) within this block's 16-float slice,
    // row-group t>>2 (128 groups), 8 rows per thread.
    const int dbase = dc * 16 + ((t & 3) << 2);
    const int rgrp  = t >> 2;  // 0..127
    const float* hb = h + (long long)b * Gq * Dq + dbase;

    float4 bf = make_float4(0.f, 0.f, 0.f, 0.f);
    float4 af = make_float4(0.f, 0.f, 0.f, 0.f);

    #pragma unroll 4
    for (int it = 0; it < Gq / 128; ++it) {
        const int g = rgrp + (it << 7);
        const float4 v = *reinterpret_cast<const float4*>(hb + g * Dq);
        const float wb = row_bf_s[g];
        const float wa = row_af_s[g];
        bf.x = fmaf(wb, v.x, bf.x);
        bf.y = fmaf(wb, v.y, bf.y);
        bf.z = fmaf(wb, v.z, bf.z);
        bf.w = fmaf(wb, v.w, bf.w);
        af.x = fmaf(wa, v.x, af.x);
        af.y = fmaf(wa, v.y, af.y);
        af.z = fmaf(wa, v.z, af.z);
        af.w = fmaf(wa, v.w, af.w);
    }

    // Wave-level reduce: sum over lane bits 2..5 (rgrp low bits).
    #pragma unroll
    for (int m = 4; m <= 32; m <<= 1) {
        bf.x += __shfl_xor(bf.x, m, 64);
        bf.y += __shfl_xor(bf.y, m, 64);
        bf.z += __shfl_xor(bf.z, m, 64);
        bf.w += __shfl_xor(bf.w, m, 64);
        af.x += __shfl_xor(af.x, m, 64);
        af.y += __shfl_xor(af.y, m, 64);
        af.z += __shfl_xor(af.z, m, 64);
        af.w += __shfl_xor(af.w, m, 64);
    }

    // Cross-wave combine (8 waves) via tiny LDS buffers.
    __shared__ float4 pbf[8][4];
    __shared__ float4 paf[8][4];
    const int wave = t >> 6;
    const int lane = t & 63;
    if (lane < 4) {
        pbf[wave][lane] = bf;
        paf[wave][lane] = af;
    }
    __syncthreads();

    if (t < 4) {  // thread t owns d-slot t of this block's slice
        float4 sb = pbf[0][t];
        float4 sa = paf[0][t];
        #pragma unroll
        for (int wv = 1; wv < 8; ++wv) {
            const float4 ob = pbf[wv][t];
            const float4 oa = paf[wv][t];
            sb.x += ob.x; sb.y += ob.y; sb.z += ob.z; sb.w += ob.w;
            sa.x += oa.x; sa.y += oa.y; sa.z += oa.z; sa.w += oa.w;
        }
        const int d = dc * 16 + (t << 2);
        *reinterpret_cast<float4*>(out + b * Dq + d) = sb;
        *reinterpret_cast<float4*>(out + Bq * Dq + b * Dq + d) = sa;
    }
}

extern "C" void kernel_launch(void* const* d_in, const int* in_sizes, int n_in,
                              void* d_out, int out_size, void* d_ws, size_t ws_size,
                              hipStream_t stream) {
    const float* h     = (const float*)d_in[0];
    const float* adj   = (const float*)d_in[1];
    const int*   phone = (const int*)d_in[2];
    float* out = (float*)d_out;

    dim3 grid(Bq, NDC);
    agg_kernel<<<grid, 512, 0, stream>>>(h, adj, phone, out);
}

// Round 4
// 16.409 us; speedup vs baseline: 1.0045x; 1.0045x over previous
//
#include <hip/hip_runtime.h>

// B=128, G=1024, D=128. Outputs: g_bf (B,D) then g_af (B,D), f32.
constexpr int Bq = 128;
constexpr int Gq = 1024;
constexpr int Dq = 128;
constexpr int NDC = 8;  // d-chunks of 16 floats (64 B) each -> grid 128 x 8

__global__ __launch_bounds__(512) void agg_kernel(
    const float* __restrict__ h,     // (B, G, D)
    const float* __restrict__ adj,   // (B, G, G)
    const int*   __restrict__ phone, // (B,)
    float*       __restrict__ out)   // [g_bf (B,D) | g_af (B,D)]
{
    const int b  = blockIdx.x;   // batch
    const int dc = blockIdx.y;   // d-chunk (16 floats)
    const int t  = threadIdx.x;  // 0..511

    // Thread t: d-slot (t&3), row-group t>>2 (0..127), 8 rows per thread.
    const int dbase = dc * 16 + ((t & 3) << 2);
    const int rgrp  = t >> 2;
    const float* hb = h + (long long)b * Gq * Dq + dbase;

    // ---- Issue ALL h loads first: independent of phone/adj, so the
    // 64-MB stream starts at cycle ~0 instead of behind the pivot chain.
    float4 v[8];
    #pragma unroll
    for (int it = 0; it < 8; ++it) {
        v[it] = *reinterpret_cast<const float4*>(hb + (rgrp + (it << 7)) * Dq);
    }

    // ---- Pivot weights, loaded directly from global (L1/L2 broadcast;
    // 64 B coalesced per wave). No LDS staging, no barrier.
    const int p = phone[b];
    const float* rowb = adj + ((long long)b * Gq + (long long)p) * Gq;
    float w[8];
    #pragma unroll
    for (int it = 0; it < 8; ++it) {
        w[it] = rowb[rgrp + (it << 7)];
    }

    float4 bf = make_float4(0.f, 0.f, 0.f, 0.f);
    float4 af = make_float4(0.f, 0.f, 0.f, 0.f);
    #pragma unroll
    for (int it = 0; it < 8; ++it) {
        const int g = rgrp + (it << 7);
        const float wb = (g < p) ? w[it] : 0.0f;  // strictly before pivot
        const float wa = (g > p) ? w[it] : 0.0f;  // strictly after pivot
        bf.x = fmaf(wb, v[it].x, bf.x);
        bf.y = fmaf(wb, v[it].y, bf.y);
        bf.z = fmaf(wb, v[it].z, bf.z);
        bf.w = fmaf(wb, v[it].w, bf.w);
        af.x = fmaf(wa, v[it].x, af.x);
        af.y = fmaf(wa, v[it].y, af.y);
        af.z = fmaf(wa, v[it].z, af.z);
        af.w = fmaf(wa, v[it].w, af.w);
    }

    // Wave-level reduce: sum over lane bits 2..5 (rgrp low 4 bits).
    #pragma unroll
    for (int m = 4; m <= 32; m <<= 1) {
        bf.x += __shfl_xor(bf.x, m, 64);
        bf.y += __shfl_xor(bf.y, m, 64);
        bf.z += __shfl_xor(bf.z, m, 64);
        bf.w += __shfl_xor(bf.w, m, 64);
        af.x += __shfl_xor(af.x, m, 64);
        af.y += __shfl_xor(af.y, m, 64);
        af.z += __shfl_xor(af.z, m, 64);
        af.w += __shfl_xor(af.w, m, 64);
    }

    // Cross-wave combine (8 waves) via tiny LDS buffers.
    __shared__ float4 pbf[8][4];
    __shared__ float4 paf[8][4];
    const int wave = t >> 6;
    const int lane = t & 63;
    if (lane < 4) {
        pbf[wave][lane] = bf;
        paf[wave][lane] = af;
    }
    __syncthreads();

    if (t < 4) {  // thread t owns d-slot t of this block's slice
        float4 sb = pbf[0][t];
        float4 sa = paf[0][t];
        #pragma unroll
        for (int wv = 1; wv < 8; ++wv) {
            const float4 ob = pbf[wv][t];
            const float4 oa = paf[wv][t];
            sb.x += ob.x; sb.y += ob.y; sb.z += ob.z; sb.w += ob.w;
            sa.x += oa.x; sa.y += oa.y; sa.z += oa.z; sa.w += oa.w;
        }
        const int d = dc * 16 + (t << 2);
        *reinterpret_cast<float4*>(out + b * Dq + d) = sb;
        *reinterpret_cast<float4*>(out + Bq * Dq + b * Dq + d) = sa;
    }
}

extern "C" void kernel_launch(void* const* d_in, const int* in_sizes, int n_in,
                              void* d_out, int out_size, void* d_ws, size_t ws_size,
                              hipStream_t stream) {
    const float* h     = (const float*)d_in[0];
    const float* adj   = (const float*)d_in[1];
    const int*   phone = (const int*)d_in[2];
    float* out = (float*)d_out;

    dim3 grid(Bq, NDC);
    agg_kernel<<<grid, 512, 0, stream>>>(h, adj, phone, out);
}

// Round 5
// 16.041 us; speedup vs baseline: 1.0276x; 1.0230x over previous
//
#include <hip/hip_runtime.h>

// B=128, G=1024, D=128. Outputs: g_bf (B,D) then g_af (B,D), f32.
constexpr int Bq = 128;
constexpr int Gq = 1024;
constexpr int Dq = 128;
constexpr int NDC = 4;  // d-chunks of 32 floats (128 B) each -> grid 128 x 4

__global__ __launch_bounds__(512) void agg_kernel(
    const float* __restrict__ h,     // (B, G, D)
    const float* __restrict__ adj,   // (B, G, G)
    const int*   __restrict__ phone, // (B,)
    float*       __restrict__ out)   // [g_bf (B,D) | g_af (B,D)]
{
    const int b  = blockIdx.x;   // batch
    const int dc = blockIdx.y;   // d-chunk (32 floats = 128 B)
    const int t  = threadIdx.x;  // 0..511

    // Thread t: d-slot t&7 (4 floats), row-group t>>3 (0..63), 16 rows/thread.
    // A wave's load instruction covers 8 rows x 128 B CONTIGUOUS segments,
    // so HBM/L2 line granularity (64/128 B) can't cause over-fetch.
    const int dbase = dc * 32 + ((t & 7) << 2);
    const int rgrp  = t >> 3;                 // 0..63
    const float* hb = h + (long long)b * Gq * Dq + dbase;

    // ---- Issue all 16 h loads up front (independent of phone/adj).
    float4 va[8], vb[8];
    #pragma unroll
    for (int it = 0; it < 8; ++it) {
        va[it] = *reinterpret_cast<const float4*>(hb + (rgrp + (it << 6)) * Dq);
    }
    #pragma unroll
    for (int it = 0; it < 8; ++it) {
        vb[it] = *reinterpret_cast<const float4*>(hb + (rgrp + ((it + 8) << 6)) * Dq);
    }

    // ---- Pivot weights straight from global (L1/L2 broadcast, no barrier).
    const int p = phone[b];
    const float* rowb = adj + ((long long)b * Gq + (long long)p) * Gq;
    float w[16];
    #pragma unroll
    for (int it = 0; it < 16; ++it) {
        w[it] = rowb[rgrp + (it << 6)];
    }

    float4 bf = make_float4(0.f, 0.f, 0.f, 0.f);
    float4 af = make_float4(0.f, 0.f, 0.f, 0.f);
    #pragma unroll
    for (int it = 0; it < 16; ++it) {
        const int g = rgrp + (it << 6);
        const float4 v = (it < 8) ? va[it] : vb[it - 8];
        const float wb = (g < p) ? w[it] : 0.0f;  // strictly before pivot
        const float wa = (g > p) ? w[it] : 0.0f;  // strictly after pivot
        bf.x = fmaf(wb, v.x, bf.x);
        bf.y = fmaf(wb, v.y, bf.y);
        bf.z = fmaf(wb, v.z, bf.z);
        bf.w = fmaf(wb, v.w, bf.w);
        af.x = fmaf(wa, v.x, af.x);
        af.y = fmaf(wa, v.y, af.y);
        af.z = fmaf(wa, v.z, af.z);
        af.w = fmaf(wa, v.w, af.w);
    }

    // Wave-level reduce: rgrp's in-wave bits are lane bits 3..5.
    #pragma unroll
    for (int m = 8; m <= 32; m <<= 1) {
        bf.x += __shfl_xor(bf.x, m, 64);
        bf.y += __shfl_xor(bf.y, m, 64);
        bf.z += __shfl_xor(bf.z, m, 64);
        bf.w += __shfl_xor(bf.w, m, 64);
        af.x += __shfl_xor(af.x, m, 64);
        af.y += __shfl_xor(af.y, m, 64);
        af.z += __shfl_xor(af.z, m, 64);
        af.w += __shfl_xor(af.w, m, 64);
    }

    // Cross-wave combine (8 waves x 8 d-slots).
    __shared__ float4 pbf[8][8];
    __shared__ float4 paf[8][8];
    const int wave = t >> 6;
    const int lane = t & 63;
    if (lane < 8) {
        pbf[wave][lane] = bf;
        paf[wave][lane] = af;
    }
    __syncthreads();

    if (t < 8) {  // thread t owns d-slot t of this block's 32-float slice
        float4 sb = pbf[0][t];
        float4 sa = paf[0][t];
        #pragma unroll
        for (int wv = 1; wv < 8; ++wv) {
            const float4 ob = pbf[wv][t];
            const float4 oa = paf[wv][t];
            sb.x += ob.x; sb.y += ob.y; sb.z += ob.z; sb.w += ob.w;
            sa.x += oa.x; sa.y += oa.y; sa.z += oa.z; sa.w += oa.w;
        }
        const int d = dc * 32 + (t << 2);
        *reinterpret_cast<float4*>(out + b * Dq + d) = sb;
        *reinterpret_cast<float4*>(out + Bq * Dq + b * Dq + d) = sa;
    }
}

extern "C" void kernel_launch(void* const* d_in, const int* in_sizes, int n_in,
                              void* d_out, int out_size, void* d_ws, size_t ws_size,
                              hipStream_t stream) {
    const float* h     = (const float*)d_in[0];
    const float* adj   = (const float*)d_in[1];
    const int*   phone = (const int*)d_in[2];
    float* out = (float*)d_out;

    dim3 grid(Bq, NDC);
    agg_kernel<<<grid, 512, 0, stream>>>(h, adj, phone, out);
}